// Round 1
// baseline (112.858 us; speedup 1.0000x reference)
//
#include <hip/hip_runtime.h>

// GaussianBlur / upfirdn2d: 4x4 separable binomial kernel [1,3,3,1]^T[1,3,3,1]/16,
// pad=(2,1) both dims, stride 1. Input/output (8,128,256,256) fp32, NCHW.
// Memory-bound: target 1 read + 1 write per element, separable conv in registers.

constexpr int H = 256;
constexpr int W = 256;
constexpr int RR = 16;              // output rows per thread-strip
constexpr int STRIPS = H / RR;      // 16 strips per image
constexpr int NIMG = 8 * 128;       // N*C images

// Horizontal 1D conv with weights [1,3,3,1] at float4 granularity.
// Thread qx owns columns x = 4*qx .. 4*qx+3. Needs inputs x-2 .. x+4.
__device__ __forceinline__ float4 hconv(const float* __restrict__ row, int qx) {
    const int x4 = qx << 2;
    const float4 c = *reinterpret_cast<const float4*>(row + x4);
    float lz = 0.f, lw = 0.f, rx = 0.f;   // zero padding at image edges
    if (qx > 0)          { lz = row[x4 - 2]; lw = row[x4 - 1]; }
    if (qx < (W / 4 - 1)) { rx = row[x4 + 4]; }
    float4 h;
    h.x = lz  + 3.f * (lw  + c.x) + c.y;
    h.y = lw  + 3.f * (c.x + c.y) + c.z;
    h.z = c.x + 3.f * (c.y + c.z) + c.w;
    h.w = c.y + 3.f * (c.z + c.w) + rx;
    return h;
}

__global__ __launch_bounds__(256) void GaussianBlur_15358803050751_kernel(
        const float* __restrict__ in, float* __restrict__ out) {
    const int tid = threadIdx.x;
    const int qx = tid & 63;            // float4 column index (W/4 == 64)
    const int ty = tid >> 6;            // 4 strips handled per block
    const int gstrip = blockIdx.x * 4 + ty;
    const int img = gstrip >> 4;        // / STRIPS
    const int s   = gstrip & (STRIPS - 1);
    const int y0  = s * RR;

    const float* __restrict__ ip = in  + (size_t)img * (H * W);
    float* __restrict__       op = out + (size_t)img * (H * W);

    const float4 zero4 = make_float4(0.f, 0.f, 0.f, 0.f);

    // Rolling window of horizontally-convolved rows: input rows y-2, y-1, y, y+1
    float4 ha = (y0 - 2 >= 0) ? hconv(ip + (size_t)(y0 - 2) * W, qx) : zero4;
    float4 hb = (y0 - 1 >= 0) ? hconv(ip + (size_t)(y0 - 1) * W, qx) : zero4;
    float4 hc = hconv(ip + (size_t)y0 * W, qx);   // y0 always in [0, H)

    #pragma unroll 4
    for (int r = 0; r < RR; ++r) {
        const int y = y0 + r;
        const float4 hd = (y + 1 < H) ? hconv(ip + (size_t)(y + 1) * W, qx) : zero4;
        float4 o;
        o.x = (ha.x + 3.f * (hb.x + hc.x) + hd.x) * 0.0625f;
        o.y = (ha.y + 3.f * (hb.y + hc.y) + hd.y) * 0.0625f;
        o.z = (ha.z + 3.f * (hb.z + hc.z) + hd.z) * 0.0625f;
        o.w = (ha.w + 3.f * (hb.w + hc.w) + hd.w) * 0.0625f;
        *reinterpret_cast<float4*>(op + (size_t)y * W + (qx << 2)) = o;
        ha = hb; hb = hc; hc = hd;
    }
}

extern "C" void kernel_launch(void* const* d_in, const int* in_sizes, int n_in,
                              void* d_out, int out_size, void* d_ws, size_t ws_size,
                              hipStream_t stream) {
    (void)in_sizes; (void)n_in; (void)d_ws; (void)ws_size; (void)out_size;
    const float* in = (const float*)d_in[0];
    float* out = (float*)d_out;
    // 1024 images * 16 strips / 4 strips-per-block = 4096 blocks
    const int blocks = NIMG * STRIPS / 4;
    GaussianBlur_15358803050751_kernel<<<blocks, 256, 0, stream>>>(in, out);
}

// Round 3
// 86.455 us; speedup vs baseline: 1.3054x; 1.3054x over previous
//
#include <hip/hip_runtime.h>

// GaussianBlur / upfirdn2d: 4x4 separable binomial [1,3,3,1] x [1,3,3,1] / 16,
// pad=(2,1), stride 1. In/out (8,128,256,256) fp32 NCHW. Memory-bound.
// One wave == one full row (64 lanes x float4 = W). Horizontal halos come from
// neighbor lanes via __shfl (no extra global/L1 traffic); vertical conv via a
// rolling 4-row register window. 1 vector load + 1 vector store per row-quad.

typedef float fvec4 __attribute__((ext_vector_type(4)));  // native vector: OK for nontemporal builtins

constexpr int H = 256;
constexpr int W = 256;
constexpr int RR = 32;               // output rows per wave-strip
constexpr int STRIPS = H / RR;       // 8 strips per image
constexpr int NIMG = 8 * 128;        // N*C images

__global__ __launch_bounds__(256) void GaussianBlur_15358803050751_kernel(
        const float* __restrict__ in, float* __restrict__ out) {
    const int tid = threadIdx.x;
    const int qx = tid & 63;             // lane == float4 column (W/4 == 64)
    const int ty = tid >> 6;             // wave id: 4 strips per block
    const int gstrip = blockIdx.x * 4 + ty;
    const int img = gstrip >> 3;         // / STRIPS
    const int s   = gstrip & (STRIPS - 1);
    const int y0  = s * RR;

    const float* __restrict__ ip = in  + (size_t)img * (H * W) + (qx << 2);
    float* __restrict__       op = out + (size_t)img * (H * W) + (qx << 2);

    // Horizontal conv [1,3,3,1]: neighbors via intra-wave shuffle.
    auto hconv = [&](fvec4 c) -> fvec4 {
        float lz = __shfl_up(c.z, 1, 64);    // row[x4-2] from lane qx-1
        float lw = __shfl_up(c.w, 1, 64);    // row[x4-1]
        float rx = __shfl_down(c.x, 1, 64);  // row[x4+4] from lane qx+1
        lz = (qx == 0)  ? 0.f : lz;          // image left zero-pad
        lw = (qx == 0)  ? 0.f : lw;
        rx = (qx == 63) ? 0.f : rx;          // image right zero-pad
        fvec4 h;
        h.x = lz  + 3.f * (lw  + c.x) + c.y;
        h.y = lw  + 3.f * (c.x + c.y) + c.z;
        h.z = c.x + 3.f * (c.y + c.z) + c.w;
        h.w = c.y + 3.f * (c.z + c.w) + rx;
        return h;
    };

    auto ldrow = [&](int y) -> fvec4 {
        return *reinterpret_cast<const fvec4*>(ip + (size_t)y * W);
    };

    const fvec4 z4 = {0.f, 0.f, 0.f, 0.f};

    // Rolling window: h of input rows y-2, y-1, y (zero rows above the image).
    fvec4 ha = (y0 >= 2) ? hconv(ldrow(y0 - 2)) : z4;
    fvec4 hb = (y0 >= 1) ? hconv(ldrow(y0 - 1)) : z4;
    fvec4 hc = hconv(ldrow(y0));

    #pragma unroll 8
    for (int r = 0; r < RR; ++r) {
        const int y = y0 + r;
        const fvec4 hd = (y + 1 < H) ? hconv(ldrow(y + 1)) : z4;
        fvec4 o = (ha + 3.f * (hb + hc) + hd) * 0.0625f;
        // Streaming output: nontemporal store keeps input halo rows in L2.
        __builtin_nontemporal_store(o, reinterpret_cast<fvec4*>(op + (size_t)y * W));
        ha = hb; hb = hc; hc = hd;
    }
}

extern "C" void kernel_launch(void* const* d_in, const int* in_sizes, int n_in,
                              void* d_out, int out_size, void* d_ws, size_t ws_size,
                              hipStream_t stream) {
    (void)in_sizes; (void)n_in; (void)d_ws; (void)ws_size; (void)out_size;
    const float* in = (const float*)d_in[0];
    float* out = (float*)d_out;
    // 1024 images * 8 strips / 4 strips-per-block = 2048 blocks
    const int blocks = NIMG * STRIPS / 4;
    GaussianBlur_15358803050751_kernel<<<blocks, 256, 0, stream>>>(in, out);
}

// Round 4
// 85.526 us; speedup vs baseline: 1.3196x; 1.0109x over previous
//
#include <hip/hip_runtime.h>

// GaussianBlur / upfirdn2d: 4x4 separable binomial [1,3,3,1] x [1,3,3,1] / 16,
// pad=(2,1), stride 1. In/out (8,128,256,256) fp32 NCHW. Memory-bound.
// One wave == one full row (64 lanes x float4 = W). Horizontal halos via __shfl,
// vertical conv via rolling 4-row register window. This revision: each wave
// processes TWO independent strips (2x memory-level parallelism) to push HBM
// utilization if the single-stream version was latency-limited.

typedef float fvec4 __attribute__((ext_vector_type(4)));

constexpr int H = 256;
constexpr int W = 256;
constexpr int RR = 32;               // output rows per strip
constexpr int STRIPS = H / RR;       // 8 strips per image
constexpr int NIMG = 8 * 128;        // N*C images
constexpr int TOTAL_STRIPS = NIMG * STRIPS;   // 8192
constexpr int HALF = TOTAL_STRIPS / 2;        // 4096

__global__ __launch_bounds__(256) void GaussianBlur_15358803050751_kernel(
        const float* __restrict__ in, float* __restrict__ out) {
    const int tid = threadIdx.x;
    const int qx = tid & 63;             // lane == float4 column (W/4 == 64)
    const int ty = tid >> 6;             // wave id within block

    const int s0 = blockIdx.x * 4 + ty;  // strip A (images 0..511)
    const int s1 = s0 + HALF;            // strip B (images 512..1023)

    const int imgA = s0 >> 3, sA = s0 & (STRIPS - 1), y0A = sA * RR;
    const int imgB = s1 >> 3, sB = s1 & (STRIPS - 1), y0B = sB * RR;

    const float* __restrict__ ipA = in  + (size_t)imgA * (H * W) + (qx << 2);
    float* __restrict__       opA = out + (size_t)imgA * (H * W) + (qx << 2);
    const float* __restrict__ ipB = in  + (size_t)imgB * (H * W) + (qx << 2);
    float* __restrict__       opB = out + (size_t)imgB * (H * W) + (qx << 2);

    // Horizontal conv [1,3,3,1]: neighbors via intra-wave shuffle.
    auto hconv = [&](fvec4 c) -> fvec4 {
        float lz = __shfl_up(c.z, 1, 64);    // row[x4-2] from lane qx-1
        float lw = __shfl_up(c.w, 1, 64);    // row[x4-1]
        float rx = __shfl_down(c.x, 1, 64);  // row[x4+4] from lane qx+1
        lz = (qx == 0)  ? 0.f : lz;          // image left zero-pad
        lw = (qx == 0)  ? 0.f : lw;
        rx = (qx == 63) ? 0.f : rx;          // image right zero-pad
        fvec4 h;
        h.x = lz  + 3.f * (lw  + c.x) + c.y;
        h.y = lw  + 3.f * (c.x + c.y) + c.z;
        h.z = c.x + 3.f * (c.y + c.z) + c.w;
        h.w = c.y + 3.f * (c.z + c.w) + rx;
        return h;
    };

    const fvec4 z4 = {0.f, 0.f, 0.f, 0.f};
    auto ld = [&](const float* p, int y) -> fvec4 {
        return *reinterpret_cast<const fvec4*>(p + (size_t)y * W);
    };

    // Rolling windows for both streams (input rows y-2, y-1, y).
    fvec4 haA = (y0A >= 2) ? hconv(ld(ipA, y0A - 2)) : z4;
    fvec4 haB = (y0B >= 2) ? hconv(ld(ipB, y0B - 2)) : z4;
    fvec4 hbA = (y0A >= 1) ? hconv(ld(ipA, y0A - 1)) : z4;
    fvec4 hbB = (y0B >= 1) ? hconv(ld(ipB, y0B - 1)) : z4;
    fvec4 hcA = hconv(ld(ipA, y0A));
    fvec4 hcB = hconv(ld(ipB, y0B));

    #pragma unroll 4
    for (int r = 0; r < RR; ++r) {
        const int yA = y0A + r;
        const int yB = y0B + r;
        // Issue both loads back-to-back (independent streams -> 2x MLP).
        const fvec4 cA = (yA + 1 < H) ? ld(ipA, yA + 1) : z4;
        const fvec4 cB = (yB + 1 < H) ? ld(ipB, yB + 1) : z4;
        const fvec4 hdA = hconv(cA);
        const fvec4 hdB = hconv(cB);
        fvec4 oA = (haA + 3.f * (hbA + hcA) + hdA) * 0.0625f;
        fvec4 oB = (haB + 3.f * (hbB + hcB) + hdB) * 0.0625f;
        __builtin_nontemporal_store(oA, reinterpret_cast<fvec4*>(opA + (size_t)yA * W));
        __builtin_nontemporal_store(oB, reinterpret_cast<fvec4*>(opB + (size_t)yB * W));
        haA = hbA; hbA = hcA; hcA = hdA;
        haB = hbB; hbB = hcB; hcB = hdB;
    }
}

extern "C" void kernel_launch(void* const* d_in, const int* in_sizes, int n_in,
                              void* d_out, int out_size, void* d_ws, size_t ws_size,
                              hipStream_t stream) {
    (void)in_sizes; (void)n_in; (void)d_ws; (void)ws_size; (void)out_size;
    const float* in = (const float*)d_in[0];
    float* out = (float*)d_out;
    // 4096 first-half strips / 4 waves-per-block = 1024 blocks (each wave
    // also handles the matching second-half strip).
    const int blocks = HALF / 4;
    GaussianBlur_15358803050751_kernel<<<blocks, 256, 0, stream>>>(in, out);
}